// Round 1
// baseline (463.874 us; speedup 1.0000x reference)
//
#include <hip/hip_runtime.h>
#include <hip/hip_bf16.h>

#define B_ 16
#define N_ 2048
#define D_ 64
#define BN_ (B_ * N_)

typedef __bf16 bf16x8 __attribute__((ext_vector_type(8)));
typedef __bf16 bf16x4 __attribute__((ext_vector_type(4)));
typedef __bf16 bf16x2 __attribute__((ext_vector_type(2)));
typedef float  f32x4  __attribute__((ext_vector_type(4)));
typedef float  f32x16 __attribute__((ext_vector_type(16)));

// load 8 bf16 from an 8B-aligned LDS address (two b64 reads)
static __device__ __forceinline__ bf16x8 ld_frag(const __bf16* p) {
  bf16x4 lo = *(const bf16x4*)p;
  bf16x4 hi = *(const bf16x4*)(p + 4);
  return __builtin_shufflevector(lo, hi, 0, 1, 2, 3, 4, 5, 6, 7);
}

// convert 16 staged floats -> bf16 frag layout [kchunk][row][8]
static __device__ __forceinline__ void stage_K(__bf16* dst, int n, int c4,
                                               const f32x4* f) {
  bf16x8 w0, w1;
#pragma unroll
  for (int i = 0; i < 4; ++i) {
    w0[i] = (__bf16)f[0][i]; w0[i + 4] = (__bf16)f[1][i];
    w1[i] = (__bf16)f[2][i]; w1[i + 4] = (__bf16)f[3][i];
  }
  *(bf16x8*)&dst[(2 * c4 + 0) * 512 + n * 8] = w0;
  *(bf16x8*)&dst[(2 * c4 + 1) * 512 + n * 8] = w1;
}

// V^T staging: v[0],v[1] = rows 2g,2g+1 ; v[2],v[3] = rows 2g+32,2g+33
static __device__ __forceinline__ void stage_V(__bf16* dst, int g, int n0,
                                               const f32x4* v) {
#pragma unroll
  for (int p = 0; p < 2; ++p) {
    const int k = 2 * g + 32 * p;
#pragma unroll
    for (int i = 0; i < 4; ++i) {
      bf16x2 pr;
      pr[0] = (__bf16)v[2 * p][i];
      pr[1] = (__bf16)v[2 * p + 1][i];
      *(bf16x2*)&dst[(n0 + i) * 68 + k] = pr;
    }
  }
}

// barrier that waits only on LDS ops (skips the vmcnt(0) NT-store drain that
// __syncthreads() emits). Memory-clobber asm on both sides pins code motion.
static __device__ __forceinline__ void barrier_lgkm() {
  asm volatile("s_waitcnt lgkmcnt(0)" ::: "memory");
  __builtin_amdgcn_s_barrier();
  asm volatile("" ::: "memory");
}

// ===================== kernel A: row sums of exp(s), 4-way col split =========
__global__ __launch_bounds__(256, 4)
void attn_sums_kernel(const float* __restrict__ Q, const float* __restrict__ K,
                      float* __restrict__ lpart_g) {
  __shared__ __bf16 QsL[4096];
  __shared__ __bf16 KsL[2][4096];
  __shared__ float  lpart[2][64];

  const int tid = threadIdx.x;
  const int blk = blockIdx.x;
  const int bb  = blk & 15;
  const int idx = blk >> 4;          // 0..127
  const int rt  = 31 - (idx >> 2);   // heavy row-tiles dispatch first
  const int q   = idx & 3;           // column quarter: cts ct ≡ q (mod 4)
  if (q > rt) return;
  const int row0 = rt * 64;
  const int lane = tid & 63;
  const int wave = tid >> 6;
  const int wr   = wave & 1;
  const int wc   = wave >> 1;
  const int ln   = lane & 31;
  const int half = lane >> 5;

  const float* Qb = Q + (size_t)bb * N_ * D_;
  const float* Kb = K + (size_t)bb * N_ * D_;

  // stage Q tile, pre-scaled by 1/sqrt(D)=0.125
  {
    const int m   = tid >> 2;
    const int c4q = tid & 3;
    const f32x4* src = (const f32x4*)(Qb + (size_t)(row0 + m) * D_ + c4q * 16);
    f32x4 f0 = src[0], f1 = src[1], f2 = src[2], f3 = src[3];
    bf16x8 w0, w1;
#pragma unroll
    for (int i = 0; i < 4; ++i) {
      w0[i]     = (__bf16)(f0[i] * 0.125f);
      w0[i + 4] = (__bf16)(f1[i] * 0.125f);
      w1[i]     = (__bf16)(f2[i] * 0.125f);
      w1[i + 4] = (__bf16)(f3[i] * 0.125f);
    }
    *(bf16x8*)&QsL[(2 * c4q + 0) * 512 + m * 8] = w0;
    *(bf16x8*)&QsL[(2 * c4q + 1) * 512 + m * 8] = w1;
  }
  __syncthreads();

  bf16x8 qf[4];
#pragma unroll
  for (int kk = 0; kk < 4; ++kk)
    qf[kk] = *(const bf16x8*)&QsL[(2 * kk + half) * 512 + (32 * wr + ln) * 8];

  const int n_st = tid >> 2;
  const int c4   = tid & 3;
  const float* Kst = Kb + (size_t)n_st * D_ + c4 * 16;

  const int nt = (rt - q) / 4 + 1;   // cts: q, q+4, ..., <= rt
  f32x4 kp[4];
  {
    const f32x4* kq = (const f32x4*)(Kst + (size_t)q * 64 * D_);
    kp[0] = kq[0]; kp[1] = kq[1]; kp[2] = kq[2]; kp[3] = kq[3];
  }
  stage_K(KsL[0], n_st, c4, kp);

  float sums[16];
#pragma unroll
  for (int r = 0; r < 16; ++r) sums[r] = 0.0f;
  __syncthreads();

#pragma unroll 1
  for (int i = 0; i < nt; ++i) {
    const int ct  = q + 4 * i;
    const int cur = i & 1;
    if (i + 1 < nt) {  // prefetch next K tile into regs
      const f32x4* kq = (const f32x4*)(Kst + (size_t)(ct + 4) * 64 * D_);
      kp[0] = kq[0]; kp[1] = kq[1]; kp[2] = kq[2]; kp[3] = kq[3];
    }
    f32x16 s;
#pragma unroll
    for (int j = 0; j < 16; ++j) s[j] = 0.0f;
#pragma unroll
    for (int kk = 0; kk < 4; ++kk) {
      bf16x8 kf = *(const bf16x8*)&KsL[cur][(2 * kk + half) * 512 + (32 * wc + ln) * 8];
      s = __builtin_amdgcn_mfma_f32_32x32x16_bf16(qf[kk], kf, s, 0, 0, 0);
    }
    const bool diag = (ct == rt);
#pragma unroll
    for (int r = 0; r < 16; ++r) {
      float e = __expf(s[r]);
      if (diag) {
        const int ro = (r & 3) + 8 * (r >> 2) + 4 * half;
        e = ((32 * wc + ln) <= (32 * wr + ro)) ? e : 0.0f;
      }
      sums[r] += e;
    }
    if (i + 1 < nt) stage_K(KsL[cur ^ 1], n_st, c4, kp);
    barrier_lgkm();
  }

  // butterfly-reduce across the 32 lanes holding each row's columns
#pragma unroll
  for (int r = 0; r < 16; ++r) {
    float v = sums[r];
    v += __shfl_xor(v, 1);
    v += __shfl_xor(v, 2);
    v += __shfl_xor(v, 4);
    v += __shfl_xor(v, 8);
    v += __shfl_xor(v, 16);
    sums[r] = v;
  }
  if (ln == 0) {  // lanes 0 and 32 of each wave; deterministic (no atomics)
#pragma unroll
    for (int r = 0; r < 16; ++r) {
      const int ro = (r & 3) + 8 * (r >> 2) + 4 * half;
      lpart[wc][32 * wr + ro] = sums[r];
    }
  }
  __syncthreads();
  if (tid < 64)
    lpart_g[(size_t)q * BN_ + (size_t)bb * N_ + row0 + tid] =
        lpart[0][tid] + lpart[1][tid];
}

// ============ kernel B: att writes + O = P.V, 2-way col-parity split =========
__global__ __launch_bounds__(256, 3)
void attn_main_kernel(const float* __restrict__ Q, const float* __restrict__ K,
                      const float* __restrict__ V, float* __restrict__ out,
                      const float* __restrict__ lpart_g) {
  __shared__ __bf16 QsL[4096];
  __shared__ __bf16 KsL[2][4096];       // double-buffered K tile (frag layout)
  __shared__ __bf16 VtL[2][4352];       // double-buffered V^T [d][k], stride 68
  __shared__ __bf16 PtW[4 * 32 * 36];   // per-wave P slab [32 rows][36]
  __shared__ float  linvL[64];

  const int tid = threadIdx.x;
  const int blk = blockIdx.x;
  const int bb  = blk & 15;
  const int idx = blk >> 4;          // 0..63
  const int rt  = 31 - (idx >> 1);   // heavy row-tiles dispatch first
  const int par = idx & 1;           // column parity: cts ct ≡ par (mod 2)
  const int row0 = rt * 64;
  const int lane = tid & 63;
  const int wave = tid >> 6;
  const int wr   = wave & 1;
  const int wc   = wave >> 1;
  const int ln   = lane & 31;
  const int half = lane >> 5;

  const float* Qb = Q + (size_t)bb * N_ * D_;
  const float* Kb = K + (size_t)bb * N_ * D_;
  const float* Vb = V + (size_t)bb * N_ * D_;
  float* Ob = out + (size_t)bb * N_ * D_;
  float* Ab = out + (size_t)B_ * N_ * D_ + (size_t)bb * N_ * N_;

  const int nt = (rt >= par) ? ((rt - par) >> 1) + 1 : 0;

  if (nt > 0) {
    // 1/rowsum from the 4 deterministic partials (fixed summation order)
    if (tid < 64) {
      const size_t base = (size_t)bb * N_ + row0 + tid;
      float t = ((lpart_g[base] + lpart_g[(size_t)BN_ + base]) +
                 lpart_g[2 * (size_t)BN_ + base]) +
                lpart_g[3 * (size_t)BN_ + base];
      linvL[tid] = 1.0f / t;
    }
    // stage Q tile, pre-scaled
    {
      const int m   = tid >> 2;
      const int c4q = tid & 3;
      const f32x4* src = (const f32x4*)(Qb + (size_t)(row0 + m) * D_ + c4q * 16);
      f32x4 f0 = src[0], f1 = src[1], f2 = src[2], f3 = src[3];
      bf16x8 w0, w1;
#pragma unroll
      for (int i = 0; i < 4; ++i) {
        w0[i]     = (__bf16)(f0[i] * 0.125f);
        w0[i + 4] = (__bf16)(f1[i] * 0.125f);
        w1[i]     = (__bf16)(f2[i] * 0.125f);
        w1[i + 4] = (__bf16)(f3[i] * 0.125f);
      }
      *(bf16x8*)&QsL[(2 * c4q + 0) * 512 + m * 8] = w0;
      *(bf16x8*)&QsL[(2 * c4q + 1) * 512 + m * 8] = w1;
    }
    __syncthreads();

    bf16x8 qf[4];
#pragma unroll
    for (int kk = 0; kk < 4; ++kk)
      qf[kk] = *(const bf16x8*)&QsL[(2 * kk + half) * 512 + (32 * wr + ln) * 8];

    float linv[16];
#pragma unroll
    for (int r = 0; r < 16; ++r) {
      const int ro = (r & 3) + 8 * (r >> 2) + 4 * half;
      linv[r] = linvL[32 * wr + ro];
    }

    const int n_st = tid >> 2;
    const int c4   = tid & 3;
    const float* Kst = Kb + (size_t)n_st * D_ + c4 * 16;
    const int gV  = tid >> 4;
    const int n0v = (tid & 15) * 4;
    const float* Vst = Vb + (size_t)(2 * gV) * D_ + n0v;

    f32x4 kp[4], vp[4];
    {
      const size_t off0 = (size_t)par * 64 * D_;
      const f32x4* kq = (const f32x4*)(Kst + off0);
      kp[0] = kq[0]; kp[1] = kq[1]; kp[2] = kq[2]; kp[3] = kq[3];
      vp[0] = *(const f32x4*)(Vst + off0);
      vp[1] = *(const f32x4*)(Vst + off0 + D_);
      vp[2] = *(const f32x4*)(Vst + off0 + 32 * D_);
      vp[3] = *(const f32x4*)(Vst + off0 + 33 * D_);
    }
    stage_K(KsL[0], n_st, c4, kp);
    stage_V(VtL[0], gV, n0v, vp);

    f32x16 o0, o1;
#pragma unroll
    for (int i = 0; i < 16; ++i) { o0[i] = 0.0f; o1[i] = 0.0f; }
    __bf16* Pt = &PtW[wave * 32 * 36];
    __syncthreads();

#pragma unroll 1
    for (int i = 0; i < nt; ++i) {
      const int ct  = par + 2 * i;
      const int cur = i & 1;
      const int c0  = ct * 64;
      if (i + 1 < nt) {  // prefetch next K+V tiles into regs
        const size_t off = (size_t)(ct + 2) * 64 * D_;
        const f32x4* kq = (const f32x4*)(Kst + off);
        kp[0] = kq[0]; kp[1] = kq[1]; kp[2] = kq[2]; kp[3] = kq[3];
        vp[0] = *(const f32x4*)(Vst + off);
        vp[1] = *(const f32x4*)(Vst + off + D_);
        vp[2] = *(const f32x4*)(Vst + off + 32 * D_);
        vp[3] = *(const f32x4*)(Vst + off + 33 * D_);
      }
      f32x16 s;
#pragma unroll
      for (int j = 0; j < 16; ++j) s[j] = 0.0f;
#pragma unroll
      for (int kk = 0; kk < 4; ++kk) {
        bf16x8 kf = *(const bf16x8*)&KsL[cur][(2 * kk + half) * 512 + (32 * wc + ln) * 8];
        s = __builtin_amdgcn_mfma_f32_32x32x16_bf16(qf[kk], kf, s, 0, 0, 0);
      }
      const bool diag = (ct == rt);
#pragma unroll
      for (int r = 0; r < 16; ++r) {
        const int ro = (r & 3) + 8 * (r >> 2) + 4 * half;
        float e = __expf(s[r]);
        if (diag) e = ((32 * wc + ln) <= (32 * wr + ro)) ? e : 0.0f;
        const float pv = e * linv[r];
        __builtin_nontemporal_store(pv,
            Ab + (size_t)(row0 + 32 * wr + ro) * N_ + c0 + 32 * wc + ln);
        Pt[ro * 36 + ln] = (__bf16)pv;   // wave-private: no barrier needed
      }
      // O partial: this wave's 32 columns only, cross-wave reduce later
#pragma unroll
      for (int kk2 = 0; kk2 < 2; ++kk2) {
        bf16x8 af = ld_frag(&Pt[ln * 36 + 16 * kk2 + 8 * half]);
        bf16x8 b0 = ld_frag(&VtL[cur][ln * 68 + 32 * wc + 16 * kk2 + 8 * half]);
        bf16x8 b1 = ld_frag(&VtL[cur][(32 + ln) * 68 + 32 * wc + 16 * kk2 + 8 * half]);
        o0 = __builtin_amdgcn_mfma_f32_32x32x16_bf16(af, b0, o0, 0, 0, 0);
        o1 = __builtin_amdgcn_mfma_f32_32x32x16_bf16(af, b1, o1, 0, 0, 0);
      }
      if (i + 1 < nt) {
        stage_K(KsL[cur ^ 1], n_st, c4, kp);
        stage_V(VtL[cur ^ 1], gV, n0v, vp);
      }
      barrier_lgkm();
    }

    // ---- cross-wave O reduction (wc=1 -> wc=0), then 2-way atomic to O ----
    float* Ored = (float*)&KsL[0][0];  // 16 KB scratch, KsL dead now
    if (wc == 1) {
#pragma unroll
      for (int r = 0; r < 16; ++r) {
        const int ro = (r & 3) + 8 * (r >> 2) + 4 * half;
        Ored[(32 * wr + ro) * 64 + ln]      = o0[r];
        Ored[(32 * wr + ro) * 64 + 32 + ln] = o1[r];
      }
    }
    __syncthreads();
    if (wc == 0) {
#pragma unroll
      for (int r = 0; r < 16; ++r) {
        const int ro = (r & 3) + 8 * (r >> 2) + 4 * half;
        float* op = Ob + (size_t)(row0 + 32 * wr + ro) * D_;
        unsafeAtomicAdd(op + ln,      o0[r] + Ored[(32 * wr + ro) * 64 + ln]);
        unsafeAtomicAdd(op + 32 + ln, o1[r] + Ored[(32 * wr + ro) * 64 + 32 + ln]);
      }
    }
  }

  // ---- zero-fill strictly-upper att columns, parity-split between blocks ----
  const int cz0 = 64 * (rt + 1);
  if (cz0 < N_) {
    f32x4 z = {0.0f, 0.0f, 0.0f, 0.0f};
#pragma unroll 1
    for (int rr = (tid >> 6); rr < 64; rr += 4) {
      float* rowp = Ab + (size_t)(row0 + rr) * N_;
      for (int x = cz0 + (tid & 63) * 4 + par * 256; x < N_; x += 512)
        __builtin_nontemporal_store(z, (f32x4*)(rowp + x));
    }
  }
}

extern "C" void kernel_launch(void* const* d_in, const int* in_sizes, int n_in,
                              void* d_out, int out_size, void* d_ws, size_t ws_size,
                              hipStream_t stream) {
  const float* Q = (const float*)d_in[0];
  const float* K = (const float*)d_in[1];
  const float* V = (const float*)d_in[2];
  (void)in_sizes; (void)n_in; (void)out_size; (void)ws_size;
  float* out = (float*)d_out;
  float* ws  = (float*)d_ws;   // 4 partial-sum slabs: 4 * B * N floats = 512 KB

  // zero partial-sum slabs (quarters with no work contribute 0) and the O
  // region of out (accumulated via exactly-2 HW f32 atomics per element)
  hipMemsetAsync(d_ws, 0, (size_t)4 * BN_ * sizeof(float), stream);
  hipMemsetAsync(d_out, 0, (size_t)B_ * N_ * D_ * sizeof(float), stream);

  attn_sums_kernel<<<dim3(2048), dim3(256), 0, stream>>>(Q, K, ws);
  attn_main_kernel<<<dim3(1024), dim3(256), 0, stream>>>(Q, K, V, out, ws);
}

// Round 2
// 455.302 us; speedup vs baseline: 1.0188x; 1.0188x over previous
//
#include <hip/hip_runtime.h>
#include <hip/hip_bf16.h>

#define B_ 16
#define N_ 2048
#define D_ 64

typedef __bf16 bf16x8 __attribute__((ext_vector_type(8)));
typedef __bf16 bf16x4 __attribute__((ext_vector_type(4)));
typedef __bf16 bf16x2 __attribute__((ext_vector_type(2)));
typedef float  f32x4  __attribute__((ext_vector_type(4)));
typedef float  f32x16 __attribute__((ext_vector_type(16)));

// load 8 bf16 from an 8B-aligned LDS address (two b64 reads)
static __device__ __forceinline__ bf16x8 ld_frag(const __bf16* p) {
  bf16x4 lo = *(const bf16x4*)p;
  bf16x4 hi = *(const bf16x4*)(p + 4);
  return __builtin_shufflevector(lo, hi, 0, 1, 2, 3, 4, 5, 6, 7);
}

// convert 16 staged floats -> bf16 frag layout [kchunk][row][8]
static __device__ __forceinline__ void stage_K(__bf16* dst, int n, int c4,
                                               const f32x4* f) {
  bf16x8 w0, w1;
#pragma unroll
  for (int i = 0; i < 4; ++i) {
    w0[i] = (__bf16)f[0][i]; w0[i + 4] = (__bf16)f[1][i];
    w1[i] = (__bf16)f[2][i]; w1[i + 4] = (__bf16)f[3][i];
  }
  *(bf16x8*)&dst[(2 * c4 + 0) * 512 + n * 8] = w0;
  *(bf16x8*)&dst[(2 * c4 + 1) * 512 + n * 8] = w1;
}

// V^T staging: v[0],v[1] = rows 2g,2g+1 ; v[2],v[3] = rows 2g+32,2g+33
static __device__ __forceinline__ void stage_V(__bf16* dst, int g, int n0,
                                               const f32x4* v) {
#pragma unroll
  for (int p = 0; p < 2; ++p) {
    const int k = 2 * g + 32 * p;
#pragma unroll
    for (int i = 0; i < 4; ++i) {
      bf16x2 pr;
      pr[0] = (__bf16)v[2 * p][i];
      pr[1] = (__bf16)v[2 * p + 1][i];
      *(bf16x2*)&dst[(n0 + i) * 68 + k] = pr;
    }
  }
}

// barrier that waits only on LDS ops (skips the vmcnt(0) NT-store drain that
// __syncthreads() emits). Memory-clobber asm on both sides pins code motion.
static __device__ __forceinline__ void barrier_lgkm() {
  asm volatile("s_waitcnt lgkmcnt(0)" ::: "memory");
  __builtin_amdgcn_s_barrier();
  asm volatile("" ::: "memory");
}

static __device__ __forceinline__ void loadK16(const float* p, size_t off, f32x4* kp) {
  const f32x4* kq = (const f32x4*)(p + off);
  kp[0] = kq[0]; kp[1] = kq[1]; kp[2] = kq[2]; kp[3] = kq[3];
}
static __device__ __forceinline__ void loadV16(const float* p, size_t off, f32x4* vp) {
  vp[0] = *(const f32x4*)(p + off);
  vp[1] = *(const f32x4*)(p + off + D_);
  vp[2] = *(const f32x4*)(p + off + 32 * D_);
  vp[3] = *(const f32x4*)(p + off + 33 * D_);
}

// one K-tile of pass A: S = Q.K^T, accumulate row sums of exp(S)
static __device__ __forceinline__ void passA_tile(const __bf16* Ks, const bf16x8* qf,
                                                  int wr, int wc, int ln, int half,
                                                  bool diag, float* sums) {
  f32x16 s;
#pragma unroll
  for (int j = 0; j < 16; ++j) s[j] = 0.0f;
#pragma unroll
  for (int kk = 0; kk < 4; ++kk) {
    bf16x8 kf = *(const bf16x8*)&Ks[(2 * kk + half) * 512 + (32 * wc + ln) * 8];
    s = __builtin_amdgcn_mfma_f32_32x32x16_bf16(qf[kk], kf, s, 0, 0, 0);
  }
#pragma unroll
  for (int r = 0; r < 16; ++r) {
    float e = __expf(s[r]);
    if (diag) {
      const int ro = (r & 3) + 8 * (r >> 2) + 4 * half;
      e = ((32 * wc + ln) <= (32 * wr + ro)) ? e : 0.0f;
    }
    sums[r] += e;
  }
}

// one K-tile of pass B: S, P = exp(S)/l, att store, O += P.V
static __device__ __forceinline__ void passB_tile(const __bf16* Ks, const __bf16* Vt,
                                                  __bf16* Pt, const bf16x8* qf,
                                                  const float* linv, float* Ab,
                                                  int row0, int ct, bool diag,
                                                  int wr, int wc, int ln, int half,
                                                  f32x16& o0, f32x16& o1) {
  const int c0 = ct * 64;
  f32x16 s;
#pragma unroll
  for (int j = 0; j < 16; ++j) s[j] = 0.0f;
#pragma unroll
  for (int kk = 0; kk < 4; ++kk) {
    bf16x8 kf = *(const bf16x8*)&Ks[(2 * kk + half) * 512 + (32 * wc + ln) * 8];
    s = __builtin_amdgcn_mfma_f32_32x32x16_bf16(qf[kk], kf, s, 0, 0, 0);
  }
#pragma unroll
  for (int r = 0; r < 16; ++r) {
    const int ro = (r & 3) + 8 * (r >> 2) + 4 * half;
    float e = __expf(s[r]);
    if (diag) e = ((32 * wc + ln) <= (32 * wr + ro)) ? e : 0.0f;
    const float pv = e * linv[r];
    __builtin_nontemporal_store(pv,
        Ab + (size_t)(row0 + 32 * wr + ro) * N_ + c0 + 32 * wc + ln);
    Pt[ro * 36 + ln] = (__bf16)pv;   // wave-private slab: no barrier needed
  }
#pragma unroll
  for (int kk2 = 0; kk2 < 2; ++kk2) {
    bf16x8 af = ld_frag(&Pt[ln * 36 + 16 * kk2 + 8 * half]);
    bf16x8 b0 = ld_frag(&Vt[ln * 68 + 32 * wc + 16 * kk2 + 8 * half]);
    bf16x8 b1 = ld_frag(&Vt[(32 + ln) * 68 + 32 * wc + 16 * kk2 + 8 * half]);
    o0 = __builtin_amdgcn_mfma_f32_32x32x16_bf16(af, b0, o0, 0, 0, 0);
    o1 = __builtin_amdgcn_mfma_f32_32x32x16_bf16(af, b1, o1, 0, 0, 0);
  }
}

__global__ __launch_bounds__(256, 2)
void General_Attention_62251255988379_kernel(const float* __restrict__ Q,
                                             const float* __restrict__ K,
                                             const float* __restrict__ V,
                                             float* __restrict__ out) {
  __shared__ __bf16 QsL[4096];
  __shared__ __bf16 KsL[2][4096];       // double-buffered K tile (frag layout)
  __shared__ __bf16 VtL[2][4352];       // double-buffered V^T [d][k], stride 68
  __shared__ __bf16 PtW[4 * 32 * 36];   // per-wave P slab [32 rows][36]
  __shared__ float  lsum[64];

  const int tid  = threadIdx.x;
  const int blk  = blockIdx.x;
  const int bb   = blk & 15;
  const int u    = blk >> 4;                       // heavy tiles dispatch first;
  const int rb   = (u < 16) ? (31 - u) : (u - 16); // CU pair (c,c+256) = const work
  const int row0 = rb * 64;
  const int lane = tid & 63;
  const int wave = tid >> 6;
  const int wr   = wave & 1;
  const int wc   = wave >> 1;
  const int ln   = lane & 31;
  const int half = lane >> 5;

  const float* Qb = Q + (size_t)bb * N_ * D_;
  const float* Kb = K + (size_t)bb * N_ * D_;
  const float* Vb = V + (size_t)bb * N_ * D_;
  float* Ob = out + (size_t)bb * N_ * D_;
  float* Ab = out + (size_t)B_ * N_ * D_ + (size_t)bb * N_ * N_;

  if (tid < 64) lsum[tid] = 0.0f;

  // ---- stage Q tile once, pre-scaled by 1/sqrt(D)=0.125 ----
  {
    const int m  = tid >> 2;
    const int c4q = tid & 3;
    const f32x4* src = (const f32x4*)(Qb + (size_t)(row0 + m) * D_ + c4q * 16);
    f32x4 f0 = src[0], f1 = src[1], f2 = src[2], f3 = src[3];
    bf16x8 w0, w1;
#pragma unroll
    for (int i = 0; i < 4; ++i) {
      w0[i]     = (__bf16)(f0[i] * 0.125f);
      w0[i + 4] = (__bf16)(f1[i] * 0.125f);
      w1[i]     = (__bf16)(f2[i] * 0.125f);
      w1[i + 4] = (__bf16)(f3[i] * 0.125f);
    }
    *(bf16x8*)&QsL[(2 * c4q + 0) * 512 + m * 8] = w0;
    *(bf16x8*)&QsL[(2 * c4q + 1) * 512 + m * 8] = w1;
  }
  __syncthreads();

  bf16x8 qf[4];
#pragma unroll
  for (int kk = 0; kk < 4; ++kk)
    qf[kk] = *(const bf16x8*)&QsL[(2 * kk + half) * 512 + (32 * wr + ln) * 8];

  const int n_st = tid >> 2;
  const int c4   = tid & 3;
  const float* Kst = Kb + (size_t)n_st * D_ + c4 * 16;
  const int nt = rb + 1;

  // ===================== pass A: row sums of exp(s) =====================
  // unroll-by-2 with named register sets: prefetch distance = 2 iterations.
  f32x4 kpA[4], kpB[4];
  loadK16(Kst, 0, kpA);
  stage_K(KsL[0], n_st, c4, kpA);
  if (nt > 1) loadK16(Kst, (size_t)64 * D_, kpB);

  float sums[16];
#pragma unroll
  for (int r = 0; r < 16; ++r) sums[r] = 0.0f;
  __syncthreads();

#pragma unroll 1
  for (int i = 0; i < nt; ) {
    // even iter: compute KsL[0]; stage tile i+1 (kpB); load tile i+2 -> kpA
    if (i + 1 < nt) stage_K(KsL[1], n_st, c4, kpB);
    if (i + 2 < nt) loadK16(Kst, (size_t)(i + 2) * 64 * D_, kpA);
    passA_tile(KsL[0], qf, wr, wc, ln, half, i == rb, sums);
    barrier_lgkm();
    if (++i >= nt) break;
    // odd iter: compute KsL[1]; stage tile i+1 (kpA); load tile i+2 -> kpB
    if (i + 1 < nt) stage_K(KsL[0], n_st, c4, kpA);
    if (i + 2 < nt) loadK16(Kst, (size_t)(i + 2) * 64 * D_, kpB);
    passA_tile(KsL[1], qf, wr, wc, ln, half, i == rb, sums);
    barrier_lgkm();
    ++i;
  }

  // butterfly-reduce across the 32 lanes holding each row's columns
#pragma unroll
  for (int r = 0; r < 16; ++r) {
    float v = sums[r];
    v += __shfl_xor(v, 1);
    v += __shfl_xor(v, 2);
    v += __shfl_xor(v, 4);
    v += __shfl_xor(v, 8);
    v += __shfl_xor(v, 16);
    sums[r] = v;
  }
  if (ln == 0) {
#pragma unroll
    for (int r = 0; r < 16; ++r) {
      const int ro = (r & 3) + 8 * (r >> 2) + 4 * half;
      atomicAdd(&lsum[32 * wr + ro], sums[r]);
    }
  }
  __syncthreads();

  float linv[16];
#pragma unroll
  for (int r = 0; r < 16; ++r) {
    const int ro = (r & 3) + 8 * (r >> 2) + 4 * half;
    linv[r] = 1.0f / lsum[32 * wr + ro];
  }

  // ===================== pass B: att writes + O = P.V =====================
  const int gV  = tid >> 4;
  const int n0v = (tid & 15) * 4;
  const float* Vst = Vb + (size_t)(2 * gV) * D_ + n0v;

  f32x4 vpA[4], vpB[4];
  loadK16(Kst, 0, kpA);
  loadV16(Vst, 0, vpA);
  stage_K(KsL[0], n_st, c4, kpA);
  stage_V(VtL[0], gV, n0v, vpA);
  if (nt > 1) {
    loadK16(Kst, (size_t)64 * D_, kpB);
    loadV16(Vst, (size_t)64 * D_, vpB);
  }

  f32x16 o0, o1;
#pragma unroll
  for (int i = 0; i < 16; ++i) { o0[i] = 0.0f; o1[i] = 0.0f; }
  __bf16* Pt = &PtW[wave * 32 * 36];
  __syncthreads();

#pragma unroll 1
  for (int i = 0; i < nt; ) {
    // even iter: compute buf 0; stage tile i+1 (B-set); load tile i+2 -> A-set
    if (i + 1 < nt) {
      stage_K(KsL[1], n_st, c4, kpB);
      stage_V(VtL[1], gV, n0v, vpB);
    }
    if (i + 2 < nt) {
      loadK16(Kst, (size_t)(i + 2) * 64 * D_, kpA);
      loadV16(Vst, (size_t)(i + 2) * 64 * D_, vpA);
    }
    passB_tile(KsL[0], VtL[0], Pt, qf, linv, Ab, row0, i, i == rb,
               wr, wc, ln, half, o0, o1);
    barrier_lgkm();
    if (++i >= nt) break;
    // odd iter: compute buf 1; stage tile i+1 (A-set); load tile i+2 -> B-set
    if (i + 1 < nt) {
      stage_K(KsL[0], n_st, c4, kpA);
      stage_V(VtL[0], gV, n0v, vpA);
    }
    if (i + 2 < nt) {
      loadK16(Kst, (size_t)(i + 2) * 64 * D_, kpB);
      loadV16(Vst, (size_t)(i + 2) * 64 * D_, vpB);
    }
    passB_tile(KsL[1], VtL[1], Pt, qf, linv, Ab, row0, i, i == rb,
               wr, wc, ln, half, o0, o1);
    barrier_lgkm();
    ++i;
  }

  // ---- cross-wave O reduction (wc=1 partials -> wc=0) and store ----
  float* Ored = (float*)&KsL[0][0];  // 16 KB scratch (spans KsL[0..1]), dead now
  if (wc == 1) {
#pragma unroll
    for (int r = 0; r < 16; ++r) {
      const int ro = (r & 3) + 8 * (r >> 2) + 4 * half;
      Ored[(32 * wr + ro) * 64 + ln]      = o0[r];
      Ored[(32 * wr + ro) * 64 + 32 + ln] = o1[r];
    }
  }
  __syncthreads();
  if (wc == 0) {
#pragma unroll
    for (int r = 0; r < 16; ++r) {
      const int ro = (r & 3) + 8 * (r >> 2) + 4 * half;
      float* op = Ob + (size_t)(row0 + 32 * wr + ro) * D_;
      __builtin_nontemporal_store(o0[r] + Ored[(32 * wr + ro) * 64 + ln], op + ln);
      __builtin_nontemporal_store(o1[r] + Ored[(32 * wr + ro) * 64 + 32 + ln], op + 32 + ln);
    }
  }

  // ---- zero-fill strictly-upper columns of att for this row tile ----
  const int cz0 = 64 * (rb + 1);
  if (cz0 < N_) {
    f32x4 z = {0.0f, 0.0f, 0.0f, 0.0f};
#pragma unroll 1
    for (int rr = (tid >> 6); rr < 64; rr += 4) {
      float* rowp = Ab + (size_t)(row0 + rr) * N_;
      for (int x = cz0 + (tid & 63) * 4; x < N_; x += 256)
        __builtin_nontemporal_store(z, (f32x4*)(rowp + x));
    }
  }
}

extern "C" void kernel_launch(void* const* d_in, const int* in_sizes, int n_in,
                              void* d_out, int out_size, void* d_ws, size_t ws_size,
                              hipStream_t stream) {
  const float* Q = (const float*)d_in[0];
  const float* K = (const float*)d_in[1];
  const float* V = (const float*)d_in[2];
  (void)in_sizes; (void)n_in; (void)out_size; (void)d_ws; (void)ws_size;
  float* out = (float*)d_out;
  General_Attention_62251255988379_kernel<<<dim3(512), dim3(256), 0, stream>>>(Q, K, V, out);
}